// Round 18
// baseline (237.795 us; speedup 1.0000x reference)
//
#include <hip/hip_runtime.h>
#include <cmath>

namespace {

typedef _Float16 half8 __attribute__((ext_vector_type(8)));
typedef float f32x4 __attribute__((ext_vector_type(4)));

constexpr int M_TOTAL = 32 * 1024;   // B*T
constexpr int K_CH    = 512;
constexpr int NV      = 640;         // G*V
constexpr int D_CV    = 128;
constexpr int NSLOT   = 10;          // 640/64

constexpr int BM = 128, BN = 128, BK = 32;
constexpr int NTILE  = NV / BN;        // 5
constexpr int NPANEL = M_TOTAL / BM;   // 256
constexpr int NBLK   = NTILE * NPANEL; // 1280 (divisible by 8)
constexpr int KT     = K_CH / BK;      // 16

// f16 hi-only logit error: sigma ~ 5e-4. Margin tau = 6e-3 (>8 sigma)
// -> P(missed argmax flip) negligible; flag rate ~0.4%; flagged rows get
// exact fp32 recompute in gvq_fix. Validated r16/r17 (absmax unchanged).
constexpr float TAU = 6e-3f;

__device__ __forceinline__ void gld16(const void* g, void* l) {
  __builtin_amdgcn_global_load_lds(
      (__attribute__((address_space(1))) void*)g,
      (__attribute__((address_space(3))) void*)l, 16, 0, 0);
}

// ---------- prep: W[512][640] f32 -> Wth f16 [640][512] + Wtf f32 [640][512]
__global__ __launch_bounds__(256)
void prep_w2(const float* __restrict__ W, _Float16* __restrict__ Wth,
             float* __restrict__ Wtf)
{
  __shared__ float tile[32][33];
  const int bk = blockIdx.x & 15;
  const int bn = blockIdx.x >> 4;
  const int k0 = bk * 32, n0 = bn * 32;
  const int t = threadIdx.x;
  const int nn = t & 31, kk = t >> 5;
  #pragma unroll
  for (int p = 0; p < 4; ++p)
    tile[kk + p * 8][nn] = W[(size_t)(k0 + kk + p * 8) * NV + n0 + nn];
  __syncthreads();
  const int kx = t & 31, nx = t >> 5;
  #pragma unroll
  for (int p = 0; p < 4; ++p) {
    const float v = tile[kx][nx + p * 8];
    const size_t o = (size_t)(n0 + nx + p * 8) * K_CH + k0 + kx;
    Wth[o] = (_Float16)v;
    Wtf[o] = v;
  }
}

// ---------- prep: x f32 -> Xh f16 (row-major [32768][512]) ------------------
__global__ __launch_bounds__(256)
void prep_xh(const float* __restrict__ x, _Float16* __restrict__ Xh)
{
  const size_t i = ((size_t)blockIdx.x * 256 + threadIdx.x) * 2;
  half8 h;
  const float4 v0 = reinterpret_cast<const float4*>(x)[i];
  const float4 v1 = reinterpret_cast<const float4*>(x)[i + 1];
  h[0] = (_Float16)v0.x; h[1] = (_Float16)v0.y;
  h[2] = (_Float16)v0.z; h[3] = (_Float16)v0.w;
  h[4] = (_Float16)v1.x; h[5] = (_Float16)v1.y;
  h[6] = (_Float16)v1.z; h[7] = (_Float16)v1.w;
  reinterpret_cast<half8*>(Xh)[i >> 1] = h;
}

// ---------- pass 1: f16 MFMA GEMM, BK=32, 32KB LDS -> 5 blocks/CU -----------
// All 1280 blocks co-resident (20 waves/CU). r6-verified staging/swizzle.
__global__ __launch_bounds__(256, 5)
void gvq_p1c(const _Float16* __restrict__ Xh, const _Float16* __restrict__ Wth,
             const float* __restrict__ bias, const float* __restrict__ u,
             float* __restrict__ pval, int* __restrict__ pidx,
             float* __restrict__ psec)
{
  // per buffer (bytes): A f16 [0,8192) | B f16 [8192,16384); rows 32 f16=64B
  __shared__ __align__(16) char lds[2][16384];   // 32 KB total

  const int chunk = NBLK / 8;
  const int nid   = (blockIdx.x % 8) * chunk + blockIdx.x / 8;
  const int panel = nid / NTILE, ntile = nid % NTILE;
  const int m0 = panel * BM, n0 = ntile * BN;

  const int t    = threadIdx.x;
  const int wv   = t >> 6, lane = t & 63;
  const int wr   = wv >> 1, wc = wv & 1;      // 2x2 wave grid, 64x64 each
  const int li   = lane & 15, q = lane >> 4;

  // staging: chunk c = i*256+t -> row c>>2, slot c&3; slot s of row r holds
  // global chunk s^((r>>1)&3)  (r6 pattern, 0 conflicts measured).
  const int r0 = t >> 2;
  const int gc = (t & 3) ^ ((t >> 3) & 3);
  const _Float16* pxa = Xh  + (size_t)(m0 + r0) * K_CH + gc * 8;
  const _Float16* pbh = Wth + (size_t)(n0 + r0) * K_CH + gc * 8;

  f32x4 acc[4][4];
  #pragma unroll
  for (int i = 0; i < 4; ++i)
    #pragma unroll
    for (int j = 0; j < 4; ++j) acc[i][j] = (f32x4){0.f, 0.f, 0.f, 0.f};

  auto stage = [&](int kt, int b) {   // 4 gld16 per thread (vmcnt += 4)
    const int ko = kt * BK;
    char* L = lds[b];
    #pragma unroll
    for (int i = 0; i < 2; ++i) {
      gld16(pxa + (size_t)i * 64 * K_CH + ko, L + i * 4096 + wv * 1024);
      gld16(pbh + (size_t)i * 64 * K_CH + ko, L + 8192 + i * 4096 + wv * 1024);
    }
  };

  // frag-read de-swizzle: row = base+li -> key (li>>1)&3; slot q of 4
  const int soff  = (q ^ ((li >> 1) & 3)) << 4;        // bytes
  const int abase = (wr * 64 + li) * 64;               // + fm*1024
  const int bbase = 8192 + (wc * 64 + li) * 64;        // + fn*1024

  stage(0, 0);
  stage(1, 1);
  #pragma unroll
  for (int kt = 0; kt < KT; ++kt) {
    const int cur = kt & 1;
    if (kt < KT - 1) asm volatile("s_waitcnt vmcnt(4)" ::: "memory");
    else             asm volatile("s_waitcnt vmcnt(0)" ::: "memory");
    __builtin_amdgcn_s_barrier();           // tile kt visible to all waves
    __builtin_amdgcn_sched_barrier(0);

    const char* L = lds[cur];
    half8 ah[4], bh[4];
    #pragma unroll
    for (int f = 0; f < 4; ++f) {
      ah[f] = *reinterpret_cast<const half8*>(L + abase + f * 1024 + soff);
      bh[f] = *reinterpret_cast<const half8*>(L + bbase + f * 1024 + soff);
    }
    // compiler-scheduled lgkm waits (r14)
    #pragma unroll
    for (int fm = 0; fm < 4; ++fm)
      #pragma unroll
      for (int fn = 0; fn < 4; ++fn)
        acc[fm][fn] = __builtin_amdgcn_mfma_f32_16x16x32_f16(
            ah[fm], bh[fn], acc[fm][fn], 0, 0, 0);
    if (kt + 2 < KT) {
      __builtin_amdgcn_s_barrier();         // all reads of buf[cur] consumed
      __builtin_amdgcn_sched_barrier(0);    // stage stays below the barrier
      stage(kt + 2, cur);                   // lands 2 iterations from now
    }
  }

  // ---- epilogue: approx vals + per-slot top-2 (max, idx, second) ----
  const int colbase = n0 + wc * 64 + li;
  float bb[4];
  #pragma unroll
  for (int fn = 0; fn < 4; ++fn) bb[fn] = bias[colbase + fn * 16];

  const int slot = ntile * 2 + wc;
  #pragma unroll
  for (int fm = 0; fm < 4; ++fm) {
    #pragma unroll
    for (int r = 0; r < 4; ++r) {
      const int m = m0 + wr * 64 + fm * 16 + q * 4 + r;
      float v1 = -INFINITY, v2 = -INFINITY;
      int   i1 = 0x7fffffff;
      #pragma unroll
      for (int fn = 0; fn < 4; ++fn) {
        const float uu  = u[(size_t)m * NV + colbase + fn * 16];
        const float gg  = -__logf(-__logf(uu));
        const float val = acc[fm][fn][r] + bb[fn] + gg;
        const int   n   = colbase + fn * 16;
        if (val > v1)      { v2 = v1; v1 = val; i1 = n; }  // first max kept
        else if (val > v2) { v2 = val; }
      }
      #pragma unroll
      for (int s = 1; s <= 8; s <<= 1) {   // merge across 16 li-lanes
        const float ov1 = __shfl_xor(v1, s);
        const int   oi1 = __shfl_xor(i1, s);
        const float ov2 = __shfl_xor(v2, s);
        const bool  win = (v1 > ov1) || (v1 == ov1 && i1 < oi1);
        const float mv2 = fmaxf(v2, ov2);
        if (win) { v2 = fmaxf(mv2, ov1); }
        else     { v2 = fmaxf(mv2, v1); v1 = ov1; i1 = oi1; }
      }
      if (li == 0) {
        pval[(size_t)m * NSLOT + slot] = v1;
        pidx[(size_t)m * NSLOT + slot] = i1;
        psec[(size_t)m * NSLOT + slot] = v2;
      }
    }
  }
}

// ---------- gather: reduce 5 slots, margin-flag, write approx winner --------
__global__ __launch_bounds__(256)
void gvq_gather3(const float* __restrict__ pval, const int* __restrict__ pidx,
                 const float* __restrict__ psec, const float* __restrict__ cv,
                 float* __restrict__ out, int* __restrict__ flagCnt,
                 int* __restrict__ flagList)
{
  const int tid  = threadIdx.x;
  const int w    = tid >> 6;
  const int lane = tid & 63;
  const int m    = blockIdx.x * 4 + w;
  const int g    = lane >> 5;

  const size_t base = (size_t)m * NSLOT + g * 5;
  float bv = pval[base], sec = -INFINITY;
  int   bi = pidx[base], bs = 0;
  #pragma unroll
  for (int s = 1; s < 5; ++s) {
    const float v = pval[base + s];
    const int   i = pidx[base + s];
    if (v > bv || (v == bv && i < bi)) { sec = fmaxf(sec, bv); bv = v; bi = i; bs = s; }
    else                               { sec = fmaxf(sec, v); }
  }
  sec = fmaxf(sec, psec[base + bs]);   // true runner-up incl. winner's slot

  if ((lane & 31) == 0 && (bv - sec) <= TAU) {
    const int idx = atomicAdd(flagCnt, 1);
    flagList[idx] = m * 2 + g;
  }
  const float4 src = *reinterpret_cast<const float4*>(
      &cv[(size_t)bi * D_CV + (lane & 31) * 4]);
  *reinterpret_cast<float4*>(&out[(size_t)m * 256 + lane * 4]) = src;
}

// ---------- fix: exact fp32 recompute of all 320 cols for flagged rows ------
__global__ __launch_bounds__(256)
void gvq_fix(const float* __restrict__ x, const float* __restrict__ Wtf,
             const float* __restrict__ bias, const float* __restrict__ u,
             const float* __restrict__ cv, float* __restrict__ out,
             const int* __restrict__ flagCnt, const int* __restrict__ flagList)
{
  __shared__ float xs[4][K_CH];
  const int w    = threadIdx.x >> 6;
  const int lane = threadIdx.x & 63;
  const int nW   = gridDim.x * 4;
  const int wid  = blockIdx.x * 4 + w;
  const int cnt  = *flagCnt;

  for (int it = wid; it < cnt; it += nW) {
    const int id = flagList[it];
    const int m = id >> 1, g = id & 1;
    {
      f32x4* dst = reinterpret_cast<f32x4*>(xs[w]);
      const f32x4* src = reinterpret_cast<const f32x4*>(x + (size_t)m * K_CH);
      dst[lane]      = src[lane];
      dst[lane + 64] = src[lane + 64];
    }
    float bvv = -INFINITY;
    int   bn  = 0x7fffffff;
    #pragma unroll 1
    for (int c = 0; c < 5; ++c) {
      const int n = g * 320 + c * 64 + lane;
      const float* wt = Wtf + (size_t)n * K_CH;
      float acc = 0.f;
      for (int k = 0; k < K_CH; k += 4) {     // serial ascending fp32
        acc = fmaf(xs[w][k + 0], wt[k + 0], acc);
        acc = fmaf(xs[w][k + 1], wt[k + 1], acc);
        acc = fmaf(xs[w][k + 2], wt[k + 2], acc);
        acc = fmaf(xs[w][k + 3], wt[k + 3], acc);
      }
      const float uu  = u[(size_t)m * NV + n];
      const float gg  = -logf(-logf(uu));
      const float val = acc + bias[n] + gg;
      if (val > bvv) { bvv = val; bn = n; }   // ascending n keeps first max
    }
    #pragma unroll
    for (int s = 1; s <= 32; s <<= 1) {
      const float ov = __shfl_xor(bvv, s);
      const int   oi = __shfl_xor(bn, s);
      if (ov > bvv || (ov == bvv && oi < bn)) { bvv = ov; bn = oi; }
    }
    if (lane < 32) {
      const float4 src = *reinterpret_cast<const float4*>(
          &cv[(size_t)bn * D_CV + lane * 4]);
      *reinterpret_cast<float4*>(&out[(size_t)m * 256 + g * 128 + lane * 4]) = src;
    }
  }
}

}  // namespace

extern "C" void kernel_launch(void* const* d_in, const int* in_sizes, int n_in,
                              void* d_out, int out_size, void* d_ws, size_t ws_size,
                              hipStream_t stream)
{
  const float* x    = (const float*)d_in[0];
  const float* W    = (const float*)d_in[1];
  const float* bias = (const float*)d_in[2];
  const float* cv   = (const float*)d_in[3];
  const float* u    = (const float*)d_in[4];
  float* out = (float*)d_out;

  _Float16* Wth   = (_Float16*)d_ws;
  float*    Wtf   = (float*)(Wth + (size_t)NV * K_CH);
  float*    pval  = Wtf + (size_t)NV * K_CH;
  int*      pidx  = (int*)(pval + (size_t)M_TOTAL * NSLOT);
  float*    psec  = (float*)(pidx + (size_t)M_TOTAL * NSLOT);
  int*      flagCnt  = (int*)(psec + (size_t)M_TOTAL * NSLOT);
  int*      flagList = flagCnt + 4;
  _Float16* Xh    = (_Float16*)(flagList + M_TOTAL * 2);

  hipMemsetAsync(flagCnt, 0, sizeof(int), stream);
  hipLaunchKernelGGL(prep_w2, dim3(320), dim3(256), 0, stream, W, Wth, Wtf);
  hipLaunchKernelGGL(prep_xh, dim3(8192), dim3(256), 0, stream, x, Xh);
  hipLaunchKernelGGL(gvq_p1c, dim3(NBLK), dim3(256), 0, stream,
                     Xh, Wth, bias, u, pval, pidx, psec);
  hipLaunchKernelGGL(gvq_gather3, dim3(M_TOTAL / 4), dim3(256), 0, stream,
                     pval, pidx, psec, cv, out, flagCnt, flagList);
  hipLaunchKernelGGL(gvq_fix, dim3(128), dim3(256), 0, stream,
                     x, Wtf, bias, u, cv, out, flagCnt, flagList);
}

// Round 19
// 201.555 us; speedup vs baseline: 1.1798x; 1.1798x over previous
//
#include <hip/hip_runtime.h>
#include <cmath>

namespace {

typedef _Float16 half8 __attribute__((ext_vector_type(8)));
typedef float f32x4 __attribute__((ext_vector_type(4)));

constexpr int M_TOTAL = 32 * 1024;   // B*T
constexpr int K_CH    = 512;
constexpr int NV      = 640;         // G*V
constexpr int D_CV    = 128;
constexpr int NSLOT   = 10;          // 640/64

constexpr int BM = 128, BN = 64, BK = 32;
constexpr int NTILE  = NV / BN;        // 10
constexpr int NPANEL = M_TOTAL / BM;   // 256
constexpr int NBLK   = NTILE * NPANEL; // 2560 (divisible by 8)
constexpr int KT     = K_CH / BK;      // 16

// f16 hi-only logit error: sigma ~ 5e-4. Margin tau = 6e-3 (>8 sigma);
// flagged rows exactly recomputed in fp32 (gvq_fix). Validated r16-r18.
constexpr float TAU = 6e-3f;

__device__ __forceinline__ void gld16(const void* g, void* l) {
  __builtin_amdgcn_global_load_lds(
      (__attribute__((address_space(1))) void*)g,
      (__attribute__((address_space(3))) void*)l, 16, 0, 0);
}

// ---------- prep: W[512][640] f32 -> Wth f16 [640][512] + Wtf f32 [640][512]
__global__ __launch_bounds__(256)
void prep_w2(const float* __restrict__ W, _Float16* __restrict__ Wth,
             float* __restrict__ Wtf)
{
  __shared__ float tile[32][33];
  const int bk = blockIdx.x & 15;
  const int bn = blockIdx.x >> 4;
  const int k0 = bk * 32, n0 = bn * 32;
  const int t = threadIdx.x;
  const int nn = t & 31, kk = t >> 5;
  #pragma unroll
  for (int p = 0; p < 4; ++p)
    tile[kk + p * 8][nn] = W[(size_t)(k0 + kk + p * 8) * NV + n0 + nn];
  __syncthreads();
  const int kx = t & 31, nx = t >> 5;
  #pragma unroll
  for (int p = 0; p < 4; ++p) {
    const float v = tile[kx][nx + p * 8];
    const size_t o = (size_t)(n0 + nx + p * 8) * K_CH + k0 + kx;
    Wth[o] = (_Float16)v;
    Wtf[o] = v;
  }
}

// ---------- prep: x f32 -> Xh f16 (row-major [32768][512]) ------------------
__global__ __launch_bounds__(256)
void prep_xh(const float* __restrict__ x, _Float16* __restrict__ Xh)
{
  const size_t i = ((size_t)blockIdx.x * 256 + threadIdx.x) * 2;
  half8 h;
  const float4 v0 = reinterpret_cast<const float4*>(x)[i];
  const float4 v1 = reinterpret_cast<const float4*>(x)[i + 1];
  h[0] = (_Float16)v0.x; h[1] = (_Float16)v0.y;
  h[2] = (_Float16)v0.z; h[3] = (_Float16)v0.w;
  h[4] = (_Float16)v1.x; h[5] = (_Float16)v1.y;
  h[6] = (_Float16)v1.z; h[7] = (_Float16)v1.w;
  reinterpret_cast<half8*>(Xh)[i >> 1] = h;
}

// ---------- pass 1: ZERO-BARRIER wave-private LDS dbuf f16 MFMA GEMM --------
// Wave tile 32x64. Each wave stages its own A (2KB) + its own B copy (4KB)
// into a private 12KB LDS region; all waits are wave-local (vmcnt/lgkmcnt).
// No s_barrier in the K-loop -> no convoying; TLP from 12 waves/CU.
__global__ __launch_bounds__(256, 3)
void gvq_p1d(const _Float16* __restrict__ Xh, const _Float16* __restrict__ Wth,
             const float* __restrict__ bias, const float* __restrict__ u,
             float* __restrict__ pval, int* __restrict__ pidx,
             float* __restrict__ psec)
{
  // per wave: 12288 B = 2 bufs x {A[32r x 64B] 2048 | B[64r x 64B] 4096}
  __shared__ __align__(16) char lds[4 * 12288];   // 48 KB -> 3 blocks/CU

  const int chunk = NBLK / 8;
  const int nid   = (blockIdx.x % 8) * chunk + blockIdx.x / 8;
  const int panel = nid / NTILE, ntile = nid % NTILE;
  const int m0 = panel * BM, n0 = ntile * BN;

  const int t    = threadIdx.x;
  const int wv   = t >> 6, lane = t & 63;
  const int li   = lane & 15, q = lane >> 4;

  char* const wbase = lds + wv * 12288;

  // staging: rows of 32 f16 = 64 B = 4 chunks; chunk ci = i*64+lane ->
  // row ci>>2, slot ci&3; slot holds global chunk slot^((row>>1)&3).
  // Per-lane constants (i-invariant, verified: i*16-row step keeps key):
  const int gc = (lane & 3) ^ ((lane >> 3) & 3);
  const _Float16* paA = Xh  + (size_t)(m0 + wv * 32 + (lane >> 2)) * K_CH + gc * 8;
  const _Float16* paB = Wth + (size_t)(n0 + (lane >> 2)) * K_CH + gc * 8;

  f32x4 acc[2][4];
  #pragma unroll
  for (int i = 0; i < 2; ++i)
    #pragma unroll
    for (int j = 0; j < 4; ++j) acc[i][j] = (f32x4){0.f, 0.f, 0.f, 0.f};

  auto stage = [&](int kt, int b) {   // 6 gld16, all wave-private (vmcnt += 6)
    const int ko = kt * BK;
    char* L = wbase + b * 6144;
    gld16(paA + ko,                       L + 0);
    gld16(paA + (size_t)16 * K_CH + ko,   L + 1024);
    gld16(paB + ko,                       L + 2048);
    gld16(paB + (size_t)16 * K_CH + ko,   L + 3072);
    gld16(paB + (size_t)32 * K_CH + ko,   L + 4096);
    gld16(paB + (size_t)48 * K_CH + ko,   L + 5120);
  };

  // frag-read de-swizzle (r6 pattern, 0 conflicts measured): row = f*16+li,
  // key (row>>1)&3 == (li>>1)&3 (16 == 0 mod 4 after >>1,&3).
  const int soff = (q ^ ((li >> 1) & 3)) << 4;   // bytes within row

  stage(0, 0);
  stage(1, 1);
  #pragma unroll
  for (int kt = 0; kt < KT; ++kt) {
    const int cur = kt & 1;
    // wave-local: my stage(kt) done; my stage(kt+1) (6 loads) stays in flight
    if (kt < KT - 1) asm volatile("s_waitcnt vmcnt(6)" ::: "memory");
    else             asm volatile("s_waitcnt vmcnt(0)" ::: "memory");
    __builtin_amdgcn_sched_barrier(0);

    const char* L = wbase + cur * 6144;
    half8 ah[2], bh[4];
    #pragma unroll
    for (int fm = 0; fm < 2; ++fm)
      ah[fm] = *reinterpret_cast<const half8*>(L + (fm * 16 + li) * 64 + soff);
    #pragma unroll
    for (int fn = 0; fn < 4; ++fn)
      bh[fn] = *reinterpret_cast<const half8*>(L + 2048 + (fn * 16 + li) * 64 + soff);
    // drain my ds_reads so re-staging buf[cur] below is safe (wave-local)
    asm volatile("s_waitcnt lgkmcnt(0)" ::: "memory");
    __builtin_amdgcn_sched_barrier(0);     // rule #18: MFMAs stay below
    if (kt + 2 < KT) stage(kt + 2, cur);   // flies under MFMA + next iter

    #pragma unroll
    for (int fm = 0; fm < 2; ++fm)
      #pragma unroll
      for (int fn = 0; fn < 4; ++fn)
        acc[fm][fn] = __builtin_amdgcn_mfma_f32_16x16x32_f16(
            ah[fm], bh[fn], acc[fm][fn], 0, 0, 0);
  }

  // ---- epilogue: approx vals + per-slot top-2 (max, idx, second) ----
  const int colbase = n0 + li;
  float bb[4];
  #pragma unroll
  for (int fn = 0; fn < 4; ++fn) bb[fn] = bias[colbase + fn * 16];

  const int slot = ntile;
  #pragma unroll
  for (int fm = 0; fm < 2; ++fm) {
    #pragma unroll
    for (int r = 0; r < 4; ++r) {
      const int m = m0 + wv * 32 + fm * 16 + q * 4 + r;
      float v1 = -INFINITY, v2 = -INFINITY;
      int   i1 = 0x7fffffff;
      #pragma unroll
      for (int fn = 0; fn < 4; ++fn) {
        const float uu  = u[(size_t)m * NV + colbase + fn * 16];
        const float gg  = -__logf(-__logf(uu));
        const float val = acc[fm][fn][r] + bb[fn] + gg;
        const int   n   = colbase + fn * 16;
        if (val > v1)      { v2 = v1; v1 = val; i1 = n; }  // first max kept
        else if (val > v2) { v2 = val; }
      }
      #pragma unroll
      for (int s = 1; s <= 8; s <<= 1) {   // merge across 16 li-lanes
        const float ov1 = __shfl_xor(v1, s);
        const int   oi1 = __shfl_xor(i1, s);
        const float ov2 = __shfl_xor(v2, s);
        const bool  win = (v1 > ov1) || (v1 == ov1 && i1 < oi1);
        const float mv2 = fmaxf(v2, ov2);
        if (win) { v2 = fmaxf(mv2, ov1); }
        else     { v2 = fmaxf(mv2, v1); v1 = ov1; i1 = oi1; }
      }
      if (li == 0) {
        pval[(size_t)m * NSLOT + slot] = v1;
        pidx[(size_t)m * NSLOT + slot] = i1;
        psec[(size_t)m * NSLOT + slot] = v2;
      }
    }
  }
}

// ---------- gather: reduce 5 slots, margin-flag, write approx winner --------
__global__ __launch_bounds__(256)
void gvq_gather3(const float* __restrict__ pval, const int* __restrict__ pidx,
                 const float* __restrict__ psec, const float* __restrict__ cv,
                 float* __restrict__ out, int* __restrict__ flagCnt,
                 int* __restrict__ flagList)
{
  const int tid  = threadIdx.x;
  const int w    = tid >> 6;
  const int lane = tid & 63;
  const int m    = blockIdx.x * 4 + w;
  const int g    = lane >> 5;

  const size_t base = (size_t)m * NSLOT + g * 5;
  float bv = pval[base], sec = -INFINITY;
  int   bi = pidx[base], bs = 0;
  #pragma unroll
  for (int s = 1; s < 5; ++s) {
    const float v = pval[base + s];
    const int   i = pidx[base + s];
    if (v > bv || (v == bv && i < bi)) { sec = fmaxf(sec, bv); bv = v; bi = i; bs = s; }
    else                               { sec = fmaxf(sec, v); }
  }
  sec = fmaxf(sec, psec[base + bs]);   // true runner-up incl. winner's slot

  if ((lane & 31) == 0 && (bv - sec) <= TAU) {
    const int idx = atomicAdd(flagCnt, 1);
    flagList[idx] = m * 2 + g;
  }
  const float4 src = *reinterpret_cast<const float4*>(
      &cv[(size_t)bi * D_CV + (lane & 31) * 4]);
  *reinterpret_cast<float4*>(&out[(size_t)m * 256 + lane * 4]) = src;
}

// ---------- fix: exact fp32 recompute of all 320 cols for flagged rows ------
__global__ __launch_bounds__(256)
void gvq_fix(const float* __restrict__ x, const float* __restrict__ Wtf,
             const float* __restrict__ bias, const float* __restrict__ u,
             const float* __restrict__ cv, float* __restrict__ out,
             const int* __restrict__ flagCnt, const int* __restrict__ flagList)
{
  __shared__ float xs[4][K_CH];
  const int w    = threadIdx.x >> 6;
  const int lane = threadIdx.x & 63;
  const int nW   = gridDim.x * 4;
  const int wid  = blockIdx.x * 4 + w;
  const int cnt  = *flagCnt;

  for (int it = wid; it < cnt; it += nW) {
    const int id = flagList[it];
    const int m = id >> 1, g = id & 1;
    {
      f32x4* dst = reinterpret_cast<f32x4*>(xs[w]);
      const f32x4* src = reinterpret_cast<const f32x4*>(x + (size_t)m * K_CH);
      dst[lane]      = src[lane];
      dst[lane + 64] = src[lane + 64];
    }
    float bvv = -INFINITY;
    int   bn  = 0x7fffffff;
    #pragma unroll 1
    for (int c = 0; c < 5; ++c) {
      const int n = g * 320 + c * 64 + lane;
      const float* wt = Wtf + (size_t)n * K_CH;
      float acc = 0.f;
      for (int k = 0; k < K_CH; k += 4) {     // serial ascending fp32
        acc = fmaf(xs[w][k + 0], wt[k + 0], acc);
        acc = fmaf(xs[w][k + 1], wt[k + 1], acc);
        acc = fmaf(xs[w][k + 2], wt[k + 2], acc);
        acc = fmaf(xs[w][k + 3], wt[k + 3], acc);
      }
      const float uu  = u[(size_t)m * NV + n];
      const float gg  = -logf(-logf(uu));
      const float val = acc + bias[n] + gg;
      if (val > bvv) { bvv = val; bn = n; }   // ascending n keeps first max
    }
    #pragma unroll
    for (int s = 1; s <= 32; s <<= 1) {
      const float ov = __shfl_xor(bvv, s);
      const int   oi = __shfl_xor(bn, s);
      if (ov > bvv || (ov == bvv && oi < bn)) { bvv = ov; bn = oi; }
    }
    if (lane < 32) {
      const float4 src = *reinterpret_cast<const float4*>(
          &cv[(size_t)bn * D_CV + lane * 4]);
      *reinterpret_cast<float4*>(&out[(size_t)m * 256 + g * 128 + lane * 4]) = src;
    }
  }
}

}  // namespace

extern "C" void kernel_launch(void* const* d_in, const int* in_sizes, int n_in,
                              void* d_out, int out_size, void* d_ws, size_t ws_size,
                              hipStream_t stream)
{
  const float* x    = (const float*)d_in[0];
  const float* W    = (const float*)d_in[1];
  const float* bias = (const float*)d_in[2];
  const float* cv   = (const float*)d_in[3];
  const float* u    = (const float*)d_in[4];
  float* out = (float*)d_out;

  _Float16* Wth   = (_Float16*)d_ws;
  float*    Wtf   = (float*)(Wth + (size_t)NV * K_CH);
  float*    pval  = Wtf + (size_t)NV * K_CH;
  int*      pidx  = (int*)(pval + (size_t)M_TOTAL * NSLOT);
  float*    psec  = (float*)(pidx + (size_t)M_TOTAL * NSLOT);
  int*      flagCnt  = (int*)(psec + (size_t)M_TOTAL * NSLOT);
  int*      flagList = flagCnt + 4;
  _Float16* Xh    = (_Float16*)(flagList + M_TOTAL * 2);

  hipMemsetAsync(flagCnt, 0, sizeof(int), stream);
  hipLaunchKernelGGL(prep_w2, dim3(320), dim3(256), 0, stream, W, Wth, Wtf);
  hipLaunchKernelGGL(prep_xh, dim3(8192), dim3(256), 0, stream, x, Xh);
  hipLaunchKernelGGL(gvq_p1d, dim3(NBLK), dim3(256), 0, stream,
                     Xh, Wth, bias, u, pval, pidx, psec);
  hipLaunchKernelGGL(gvq_gather3, dim3(M_TOTAL / 4), dim3(256), 0, stream,
                     pval, pidx, psec, cv, out, flagCnt, flagList);
  hipLaunchKernelGGL(gvq_fix, dim3(128), dim3(256), 0, stream,
                     x, Wtf, bias, u, cv, out, flagCnt, flagList);
}

// Round 20
// 122.692 us; speedup vs baseline: 1.9381x; 1.6428x over previous
//
#include <hip/hip_runtime.h>
#include <cmath>

namespace {

typedef _Float16 half8 __attribute__((ext_vector_type(8)));
typedef float f32x4 __attribute__((ext_vector_type(4)));

constexpr int M_TOTAL = 32 * 1024;   // B*T
constexpr int K_CH    = 512;
constexpr int NV      = 640;         // G*V
constexpr int D_CV    = 128;
constexpr int NSLOT   = 10;          // 640/64

constexpr int BM = 128, BN = 128, BK = 32;
constexpr int NTILE  = NV / BN;        // 5
constexpr int NPANEL = M_TOTAL / BM;   // 256
constexpr int NBLK   = NTILE * NPANEL; // 1280 (divisible by 8)
constexpr int KT     = K_CH / BK;      // 16

// Asymmetric split scaling: lo planes x64 (f16-normal), opposing hi /64
// (exact exponent shift) => all three products land at TRUE scale ->
// single accumulator (64 VGPRs freed vs dual-acc).
constexpr float LO_UP = 64.0f;

__device__ __forceinline__ void gld16(const void* g, void* l) {
  __builtin_amdgcn_global_load_lds(
      (__attribute__((address_space(1))) void*)g,
      (__attribute__((address_space(3))) void*)l, 16, 0, 0);
}

// ---------- prep: W[512][640] f32 -> Wth/Wtl [640][512] f16 (k-major) -------
__global__ __launch_bounds__(256)
void prep_w(const float* __restrict__ W, _Float16* __restrict__ Wth,
            _Float16* __restrict__ Wtl)
{
  __shared__ float tile[32][33];
  const int bk = blockIdx.x & 15;
  const int bn = blockIdx.x >> 4;
  const int k0 = bk * 32, n0 = bn * 32;
  const int t = threadIdx.x;
  const int nn = t & 31, kk = t >> 5;
  #pragma unroll
  for (int p = 0; p < 4; ++p)
    tile[kk + p * 8][nn] = W[(size_t)(k0 + kk + p * 8) * NV + n0 + nn];
  __syncthreads();
  const int kx = t & 31, nx = t >> 5;
  #pragma unroll
  for (int p = 0; p < 4; ++p) {
    const float v = tile[kx][nx + p * 8];
    const _Float16 h = (_Float16)v;
    const _Float16 l = (_Float16)((v - (float)h) * LO_UP);
    const size_t o = (size_t)(n0 + nx + p * 8) * K_CH + k0 + kx;
    Wth[o] = h;
    Wtl[o] = l;
  }
}

// ---------- main: single-accumulator split-f16 MFMA GEMM --------------------
__global__ __launch_bounds__(256, 2)
void gvq_mfma13(const float* __restrict__ x,
                const _Float16* __restrict__ Wth, const _Float16* __restrict__ Wtl,
                const float* __restrict__ bias, const float* __restrict__ u,
                float* __restrict__ pval, int* __restrict__ pidx)
{
  // per buffer (bytes): As f32 [0,16384) | Bh [16384,24576) | Bl [24576,32768)
  __shared__ __align__(16) char lds[2][32768];   // 64 KB

  const int chunk = NBLK / 8;
  const int nid   = (blockIdx.x % 8) * chunk + blockIdx.x / 8;
  const int panel = nid / NTILE, ntile = nid % NTILE;
  const int m0 = panel * BM, n0 = ntile * BN;

  const int t    = threadIdx.x;
  const int wv   = t >> 6, lane = t & 63;
  const int wr   = wv >> 1, wc = wv & 1;      // 2x2 wave grid, 64x64 each
  const int li   = lane & 15, q = lane >> 4;

  // staging source (pre-swizzled global chunk; LDS dest stays linear)
  const int gca = (t & 7) ^ ((t >> 3) & 7);           // A: 16B chunk of 8
  const float* pxa = x + (size_t)(m0 + (t >> 3)) * K_CH + gca * 4;
  const int gcb = (t & 3) ^ ((t >> 3) & 3);           // B: 16B chunk of 4
  const _Float16* pbh = Wth + (size_t)(n0 + (t >> 2)) * K_CH + gcb * 8;
  const _Float16* pbl = Wtl + (size_t)(n0 + (t >> 2)) * K_CH + gcb * 8;

  f32x4 acc[4][4];    // single accumulator (true scale)
  #pragma unroll
  for (int i = 0; i < 4; ++i)
    #pragma unroll
    for (int j = 0; j < 4; ++j)
      acc[i][j] = (f32x4){0.f, 0.f, 0.f, 0.f};

  auto stage = [&](int kt, int b) {   // 8 gld16 per thread (vmcnt += 8)
    const int ko = kt * BK;
    char* L = lds[b];
    #pragma unroll
    for (int i = 0; i < 4; ++i)
      gld16(pxa + (size_t)i * 32 * K_CH + ko, L + i * 4096 + wv * 1024);
    #pragma unroll
    for (int i = 0; i < 2; ++i) {
      gld16(pbh + (size_t)i * 64 * K_CH + ko, L + 16384 + i * 4096 + wv * 1024);
      gld16(pbl + (size_t)i * 64 * K_CH + ko, L + 24576 + i * 4096 + wv * 1024);
    }
  };

  // frag-read de-swizzled offsets (bytes)
  const int abase = (wr * 64 + li) * 128;              // + fm*2048
  const int s0 = (((q * 2 + 0) ^ (li & 7)) << 4);
  const int s1 = (((q * 2 + 1) ^ (li & 7)) << 4);
  const int bboff = (wc * 64 + li) * 64 + ((q ^ ((li >> 1) & 3)) << 4); // + fn*1024

  const int colbase = n0 + wc * 64 + li;
  const _Float16 hd = (_Float16)(1.0f / 64.0f);
  float ureg[4][4][4];   // prefetched in last K-step (bounded live range)
  float bb[4];

  stage(0, 0);
  stage(1, 1);
  #pragma unroll
  for (int kt = 0; kt < KT; ++kt) {
    const int cur = kt & 1;
    if (kt < KT - 1) asm volatile("s_waitcnt vmcnt(8)" ::: "memory");
    else             asm volatile("s_waitcnt vmcnt(0)" ::: "memory");
    __builtin_amdgcn_s_barrier();           // tile kt visible to all waves
    __builtin_amdgcn_sched_barrier(0);      // nothing hoists above the barrier

    const char* L = lds[cur];
    half8 bh[4], bl[4], bhd[4];
    f32x4 af0[4], af1[4];
    #pragma unroll
    for (int fn = 0; fn < 4; ++fn) {
      bh[fn] = *reinterpret_cast<const half8*>(L + 16384 + fn * 1024 + bboff);
      bl[fn] = *reinterpret_cast<const half8*>(L + 24576 + fn * 1024 + bboff);
    }
    #pragma unroll
    for (int fm = 0; fm < 4; ++fm) {
      af0[fm] = *reinterpret_cast<const f32x4*>(L + abase + fm * 2048 + s0);
      af1[fm] = *reinterpret_cast<const f32x4*>(L + abase + fm * 2048 + s1);
    }

    if (kt == KT - 1) {
      // epilogue operand prefetch: flies under the final MFMA cluster.
      #pragma unroll
      for (int fm = 0; fm < 4; ++fm)
        #pragma unroll
        for (int r = 0; r < 4; ++r) {
          const int m = m0 + wr * 64 + fm * 16 + q * 4 + r;
          #pragma unroll
          for (int fn = 0; fn < 4; ++fn)
            ureg[fm][r][fn] = u[(size_t)m * NV + colbase + fn * 16];
        }
      #pragma unroll
      for (int fn = 0; fn < 4; ++fn) bb[fn] = bias[colbase + fn * 16];
    }

    #pragma unroll
    for (int fn = 0; fn < 4; ++fn) {
      half8 d;
      #pragma unroll
      for (int e = 0; e < 8; ++e) d[e] = bh[fn][e] * hd;   // exact /64
      bhd[fn] = d;
    }
    #pragma unroll
    for (int fm = 0; fm < 4; ++fm) {
      half8 ah, al, ahd;                    // split on the fly
      #pragma unroll
      for (int e = 0; e < 4; ++e) {
        const float v0 = af0[fm][e], v1 = af1[fm][e];
        const _Float16 h0 = (_Float16)v0, h1 = (_Float16)v1;
        ah[e]      = h0; al[e]      = (_Float16)((v0 - (float)h0) * LO_UP);
        ah[4 + e]  = h1; al[4 + e]  = (_Float16)((v1 - (float)h1) * LO_UP);
        ahd[e]     = h0 * hd;
        ahd[4 + e] = h1 * hd;
      }
      #pragma unroll
      for (int fn = 0; fn < 4; ++fn) {
        acc[fm][fn] = __builtin_amdgcn_mfma_f32_16x16x32_f16(
            ah, bh[fn], acc[fm][fn], 0, 0, 0);        // hi*hi
        acc[fm][fn] = __builtin_amdgcn_mfma_f32_16x16x32_f16(
            ahd, bl[fn], acc[fm][fn], 0, 0, 0);       // (h/64)*(64*lo_w)
        acc[fm][fn] = __builtin_amdgcn_mfma_f32_16x16x32_f16(
            al, bhd[fn], acc[fm][fn], 0, 0, 0);       // (64*lo_x)*(h_w/64)
      }
    }
    if (kt + 2 < KT) {
      __builtin_amdgcn_s_barrier();         // all reads of buf[cur] consumed
      __builtin_amdgcn_sched_barrier(0);    // stage stays below the barrier
      stage(kt + 2, cur);                   // lands 2 iterations from now
    }
  }

  // ---- epilogue: bias + gumbel (fast log), argmax per 64-col slot ----
  const int slot = ntile * 2 + wc;
  #pragma unroll
  for (int fm = 0; fm < 4; ++fm) {
    #pragma unroll
    for (int r = 0; r < 4; ++r) {
      const int m = m0 + wr * 64 + fm * 16 + q * 4 + r;
      float bv = -INFINITY;
      int   bi = 0x7fffffff;
      #pragma unroll
      for (int fn = 0; fn < 4; ++fn) {
        const float uu  = ureg[fm][r][fn];
        const float g   = -__logf(-__logf(uu));
        const float val = acc[fm][fn][r] + bb[fn] + g;
        const int   n   = colbase + fn * 16;
        if (val > bv) { bv = val; bi = n; }   // fn ascending => first max kept
      }
      #pragma unroll
      for (int s = 1; s <= 8; s <<= 1) {      // reduce over 16 li-lanes
        const float ov = __shfl_xor(bv, s);
        const int   oi = __shfl_xor(bi, s);
        if (ov > bv || (ov == bv && oi < bi)) { bv = ov; bi = oi; }
      }
      if (li == 0) {
        pval[(size_t)m * NSLOT + slot] = bv;
        pidx[(size_t)m * NSLOT + slot] = bi;
      }
    }
  }
}

// ---------- reduce 5 partials per (m,g), gather codevector ----------
__global__ __launch_bounds__(256)
void gvq_gather(const float* __restrict__ pval,
                const int*   __restrict__ pidx,
                const float* __restrict__ cv,
                float* __restrict__ out)
{
  const int tid  = threadIdx.x;
  const int w    = tid >> 6;
  const int lane = tid & 63;
  const int m    = blockIdx.x * 4 + w;
  const int g    = lane >> 5;

  const float* pv = &pval[(size_t)m * NSLOT + g * 5];
  const int*   pi = &pidx[(size_t)m * NSLOT + g * 5];
  float bv = pv[0];
  int   bi = pi[0];
  #pragma unroll
  for (int s = 1; s < 5; ++s) {
    const float v = pv[s];
    const int   i = pi[s];
    if (v > bv || (v == bv && i < bi)) { bv = v; bi = i; }
  }
  const float4 src = *reinterpret_cast<const float4*>(
      &cv[(size_t)bi * D_CV + (lane & 31) * 4]);
  *reinterpret_cast<float4*>(&out[(size_t)m * 256 + lane * 4]) = src;
}

}  // namespace

extern "C" void kernel_launch(void* const* d_in, const int* in_sizes, int n_in,
                              void* d_out, int out_size, void* d_ws, size_t ws_size,
                              hipStream_t stream)
{
  const float* x    = (const float*)d_in[0];
  const float* W    = (const float*)d_in[1];
  const float* bias = (const float*)d_in[2];
  const float* cv   = (const float*)d_in[3];
  const float* u    = (const float*)d_in[4];
  float* out = (float*)d_out;

  _Float16* Wth  = (_Float16*)d_ws;
  _Float16* Wtl  = Wth + (size_t)NV * K_CH;
  float*    pval = (float*)(Wtl + (size_t)NV * K_CH);
  int*      pidx = (int*)(pval + (size_t)M_TOTAL * NSLOT);

  hipLaunchKernelGGL(prep_w, dim3(320), dim3(256), 0, stream, W, Wth, Wtl);
  hipLaunchKernelGGL(gvq_mfma13, dim3(NBLK), dim3(256), 0, stream,
                     x, Wth, Wtl, bias, u, pval, pidx);
  hipLaunchKernelGGL(gvq_gather, dim3(M_TOTAL / 4), dim3(256), 0, stream,
                     pval, pidx, cv, out);
}